// Round 1
// baseline (2586.661 us; speedup 1.0000x reference)
//
#include <hip/hip_runtime.h>
#include <hip/hip_bf16.h>
#include <math.h>

#define T_TF   11
#define H_DIM  1024
#define D_HID  512
#define NPAIR  55
#define NBATCH 2048

__device__ __forceinline__ float wave_sum(float v) {
    #pragma unroll
    for (int off = 32; off >= 1; off >>= 1)
        v += __shfl_xor(v, off, 64);
    return v;
}

__launch_bounds__(256, 2)
__global__ void energy_fused_kernel(
    const float* __restrict__ h_stack,
    const float* __restrict__ base_conf,
    const float* __restrict__ kW1, const float* __restrict__ kb1,
    const float* __restrict__ kW2, const float* __restrict__ kb2,
    const float* __restrict__ lW1, const float* __restrict__ lb1,
    const float* __restrict__ lW2, const float* __restrict__ lb2,
    const float* __restrict__ dW1, const float* __restrict__ db1,
    const float* __restrict__ dW2, const float* __restrict__ db2,
    const float* __restrict__ kwp, const float* __restrict__ lwp,
    const float* __restrict__ iwp, const float* __restrict__ tmpp,
    float* __restrict__ out)
{
    __shared__ float hsh[T_TF * H_DIM];       // 45056 B
    __shared__ float red[4][68];              // reduction scratch

    const int tid = threadIdx.x;
    const int b   = blockIdx.x;

    // pair index tables (triu k=1 order, same as np.triu_indices(11,1))
    constexpr int II[NPAIR] = {
        0,0,0,0,0,0,0,0,0,0,
        1,1,1,1,1,1,1,1,1,
        2,2,2,2,2,2,2,2,
        3,3,3,3,3,3,3,
        4,4,4,4,4,4,
        5,5,5,5,5,
        6,6,6,6,
        7,7,7,
        8,8,
        9};
    constexpr int JJ[NPAIR] = {
        1,2,3,4,5,6,7,8,9,10,
        2,3,4,5,6,7,8,9,10,
        3,4,5,6,7,8,9,10,
        4,5,6,7,8,9,10,
        5,6,7,8,9,10,
        6,7,8,9,10,
        7,8,9,10,
        8,9,10,
        9,10,
        10};

    // ---- stage h[b] (11x1024 f32) into LDS, float4 coalesced ----
    {
        const float4* hb4 = (const float4*)(h_stack + (size_t)b * (T_TF * H_DIM));
        float4* hs4 = (float4*)hsh;
        #pragma unroll
        for (int i = 0; i < (T_TF * H_DIM / 4) / 256; ++i)   // 11 iters
            hs4[tid + i * 256] = hb4[tid + i * 256];
    }
    __syncthreads();

    // ================= phase A: kinetic + local nets =================
    // thread owns hidden column d = tid + pass*256 (2 passes over 512)
    float sk = 0.f;           // sum over (t, d-owned) of relu(.)*kW2[d]
    float pl[T_TF];           // per-t partial of local net (relu after full d-sum? no:
                              // relu applies to hid per-d, then dot with lW2 -> linear in d: OK per-thread)
    #pragma unroll
    for (int t = 0; t < T_TF; ++t) pl[t] = 0.f;

    #pragma unroll 1
    for (int pass = 0; pass < 2; ++pass) {
        const int d = tid + pass * 256;
        float accK[T_TF], accL[T_TF];
        #pragma unroll
        for (int t = 0; t < T_TF; ++t) { accK[t] = 0.f; accL[t] = 0.f; }
        const float* wk = kW1 + d;
        const float* wl = lW1 + d;
        #pragma unroll 2
        for (int k = 0; k < H_DIM; k += 4) {
            const float wk0 = wk[(k+0)*D_HID], wk1 = wk[(k+1)*D_HID];
            const float wk2v= wk[(k+2)*D_HID], wk3 = wk[(k+3)*D_HID];
            const float wl0 = wl[(k+0)*D_HID], wl1 = wl[(k+1)*D_HID];
            const float wl2v= wl[(k+2)*D_HID], wl3 = wl[(k+3)*D_HID];
            #pragma unroll
            for (int t = 0; t < T_TF; ++t) {
                const float4 h4 = *(const float4*)&hsh[t * H_DIM + k];
                accK[t] = fmaf(h4.x, wk0, accK[t]);
                accK[t] = fmaf(h4.y, wk1, accK[t]);
                accK[t] = fmaf(h4.z, wk2v, accK[t]);
                accK[t] = fmaf(h4.w, wk3, accK[t]);
                accL[t] = fmaf(h4.x, wl0, accL[t]);
                accL[t] = fmaf(h4.y, wl1, accL[t]);
                accL[t] = fmaf(h4.z, wl2v, accL[t]);
                accL[t] = fmaf(h4.w, wl3, accL[t]);
            }
        }
        const float w2k = kW2[d], w2l = lW2[d];
        const float bk = kb1[d], bl = lb1[d];
        #pragma unroll
        for (int t = 0; t < T_TF; ++t) {
            const float hk = fmaxf(accK[t] + bk, 0.f);
            sk = fmaf(hk, w2k, sk);
            const float hl = fmaxf(accL[t] + bl, 0.f);
            pl[t] = fmaf(hl, w2l, pl[t]);
        }
    }

    // ================= phase B: pairwise interaction net =================
    float accP[NPAIR];
    #pragma unroll
    for (int p = 0; p < NPAIR; ++p) accP[p] = 0.f;

    const float* dW1a = dW1;
    const float* dW1b = dW1 + H_DIM * H_DIM;

    #pragma unroll 1
    for (int pass = 0; pass < 4; ++pass) {
        const int d = tid + pass * 256;
        float pi[T_TF], pj[T_TF];
        #pragma unroll
        for (int t = 0; t < T_TF; ++t) { pi[t] = 0.f; pj[t] = 0.f; }
        const float* wa = dW1a + d;
        const float* wb = dW1b + d;
        #pragma unroll 2
        for (int k = 0; k < H_DIM; k += 4) {
            const float wa0 = wa[(k+0)*H_DIM], wa1 = wa[(k+1)*H_DIM];
            const float wa2 = wa[(k+2)*H_DIM], wa3 = wa[(k+3)*H_DIM];
            const float wb0 = wb[(k+0)*H_DIM], wb1 = wb[(k+1)*H_DIM];
            const float wb2 = wb[(k+2)*H_DIM], wb3 = wb[(k+3)*H_DIM];
            #pragma unroll
            for (int t = 0; t < T_TF; ++t) {
                const float4 h4 = *(const float4*)&hsh[t * H_DIM + k];
                pi[t] = fmaf(h4.x, wa0, pi[t]);
                pi[t] = fmaf(h4.y, wa1, pi[t]);
                pi[t] = fmaf(h4.z, wa2, pi[t]);
                pi[t] = fmaf(h4.w, wa3, pi[t]);
                pj[t] = fmaf(h4.x, wb0, pj[t]);
                pj[t] = fmaf(h4.y, wb1, pj[t]);
                pj[t] = fmaf(h4.z, wb2, pj[t]);
                pj[t] = fmaf(h4.w, wb3, pj[t]);
            }
        }
        const float bias = db1[d];
        const float w2 = dW2[d];
        #pragma unroll
        for (int p = 0; p < NPAIR; ++p) {
            const float v = pi[II[p]] + pj[JJ[p]] + bias;
            accP[p] = fmaf(fmaxf(v, 0.f), w2, accP[p]);
        }
    }

    // ================= block reduction (67 scalars) =================
    const int lane = tid & 63;
    const int wv   = tid >> 6;
    {
        float r = wave_sum(sk);
        if (lane == 0) red[wv][0] = r;
        #pragma unroll
        for (int t = 0; t < T_TF; ++t) {
            r = wave_sum(pl[t]);
            if (lane == 0) red[wv][1 + t] = r;
        }
        #pragma unroll
        for (int p = 0; p < NPAIR; ++p) {
            r = wave_sum(accP[p]);
            if (lane == 0) red[wv][12 + p] = r;
        }
    }
    __syncthreads();

    if (tid == 0) {
        const float kwv = kwp[0], lwv = lwp[0], iwv = iwp[0], temp = tmpp[0];
        const float ksum = red[0][0] + red[1][0] + red[2][0] + red[3][0];
        const float kinetic = -kwv * (ksum * (1.f / T_TF) + kb2[0]);

        float lsum = 0.f;
        #pragma unroll
        for (int t = 0; t < T_TF; ++t) {
            const float lp = red[0][1+t] + red[1][1+t] + red[2][1+t] + red[3][1+t] + lb2[0];
            lsum += fmaxf(lp, 0.f);
        }
        const float local_e = lwv * (lsum * (1.f / T_TF));

        float isum = 0.f;
        #pragma unroll
        for (int p = 0; p < NPAIR; ++p) {
            float dis = red[0][12+p] + red[1][12+p] + red[2][12+p] + red[3][12+p] + db2[0];
            dis = fmaxf(dis, 0.f);
            isum += dis * (1.f / (float)(JJ[p] - II[p] + 1));
        }
        const float inter = iwv * (isum * (1.f / NPAIR));

        const float total = kinetic + local_e + inter;
        const float ec = 1.f / (1.f + expf(total / (fabsf(temp) + 0.1f)));

        out[0 * NBATCH + b] = total;
        out[1 * NBATCH + b] = kinetic;
        out[2 * NBATCH + b] = local_e;
        out[3 * NBATCH + b] = inter;
        out[4 * NBATCH + b] = ec;
        out[5 * NBATCH + b] = base_conf[b] * ec;
    }
}

extern "C" void kernel_launch(void* const* d_in, const int* in_sizes, int n_in,
                              void* d_out, int out_size, void* d_ws, size_t ws_size,
                              hipStream_t stream) {
    const float* h_stack   = (const float*)d_in[0];
    const float* base_conf = (const float*)d_in[1];
    const float* kW1 = (const float*)d_in[2];
    const float* kb1 = (const float*)d_in[3];
    const float* kW2 = (const float*)d_in[4];
    const float* kb2 = (const float*)d_in[5];
    const float* lW1 = (const float*)d_in[6];
    const float* lb1 = (const float*)d_in[7];
    const float* lW2 = (const float*)d_in[8];
    const float* lb2 = (const float*)d_in[9];
    const float* dW1 = (const float*)d_in[10];
    const float* db1 = (const float*)d_in[11];
    const float* dW2 = (const float*)d_in[12];
    const float* db2 = (const float*)d_in[13];
    const float* kwp = (const float*)d_in[14];
    const float* lwp = (const float*)d_in[15];
    const float* iwp = (const float*)d_in[16];
    const float* tmpp= (const float*)d_in[17];
    float* out = (float*)d_out;

    hipLaunchKernelGGL(energy_fused_kernel, dim3(NBATCH), dim3(256), 0, stream,
                       h_stack, base_conf, kW1, kb1, kW2, kb2,
                       lW1, lb1, lW2, lb2, dW1, db1, dW2, db2,
                       kwp, lwp, iwp, tmpp, out);
}

// Round 2
// 484.725 us; speedup vs baseline: 5.3364x; 5.3364x over previous
//
#include <hip/hip_runtime.h>
#include <hip/hip_bf16.h>
#include <math.h>

typedef __attribute__((ext_vector_type(8))) short bf16x8;
typedef __attribute__((ext_vector_type(4))) float f32x4;

#define NBATCH   2048
#define GB       4
#define ROWS     44            // GB * 11
#define ROWSP    48            // padded to 3 M-tiles
#define LDSA_BYTES (ROWSP * 1024 * 2)          // 98304
#define STG_TILE   (ROWSP * 20)                // floats per stage tile (stride 20 for banks+align)
#define STG_WAVE   (2 * STG_TILE)              // 1920 floats per wave
#define LDS_TOTAL  (LDSA_BYTES + 8 * STG_WAVE * 4)   // 98304 + 61440 = 159744

static constexpr int II_[55] = {
    0,0,0,0,0,0,0,0,0,0, 1,1,1,1,1,1,1,1,1, 2,2,2,2,2,2,2,2,
    3,3,3,3,3,3,3, 4,4,4,4,4,4, 5,5,5,5,5, 6,6,6,6, 7,7,7, 8,8, 9};
static constexpr int JJ_[55] = {
    1,2,3,4,5,6,7,8,9,10, 2,3,4,5,6,7,8,9,10, 3,4,5,6,7,8,9,10,
    4,5,6,7,8,9,10, 5,6,7,8,9,10, 6,7,8,9,10, 7,8,9,10, 8,9,10, 9,10, 10};

__device__ __forceinline__ unsigned short f32_to_bf16u(float f) {
    unsigned u = __float_as_uint(f);
    u += 0x7fffu + ((u >> 16) & 1u);
    return (unsigned short)(u >> 16);
}

// ---- weight conversion: f32 row-major (k,col) -> bf16 col-major ws[col][k] ----
// cols: [0,512)=kW1, [512,1024)=lW1, [1024,2048)=dW1a, [2048,3072)=dW1b
__global__ void convert_weights(const float* __restrict__ kW1,
                                const float* __restrict__ lW1,
                                const float* __restrict__ dW1,
                                unsigned short* __restrict__ wsB) {
    __shared__ unsigned short tile[64][65];
    const int kb = (blockIdx.x / 48) * 64;
    const int cb = (blockIdx.x % 48) * 64;
    #pragma unroll 4
    for (int i = 0; i < 16; ++i) {
        int idx = threadIdx.x + i * 256;
        int r = idx >> 6;          // k offset
        int c = idx & 63;          // col offset
        int k = kb + r, col = cb + c;
        float v;
        if (col < 512)        v = kW1[k * 512 + col];
        else if (col < 1024)  v = lW1[k * 512 + (col - 512)];
        else if (col < 2048)  v = dW1[(size_t)k * 1024 + (col - 1024)];
        else                  v = dW1[(size_t)(1024 + k) * 1024 + (col - 2048)];
        tile[c][r] = f32_to_bf16u(v);
    }
    __syncthreads();
    #pragma unroll 4
    for (int i = 0; i < 16; ++i) {
        int idx = threadIdx.x + i * 256;
        int c2 = idx >> 6;
        int r2 = idx & 63;
        wsB[(size_t)(cb + c2) * 1024 + (kb + r2)] = tile[c2][r2];
    }
}

template<bool WS>
__device__ __forceinline__ bf16x8 loadB(const unsigned short* bp, const float* fp, int fs, int k0) {
    bf16x8 r;
    if constexpr (WS) {
        r = *(const bf16x8*)(bp + k0);
    } else {
        #pragma unroll
        for (int j = 0; j < 8; ++j) r[j] = (short)f32_to_bf16u(fp[(size_t)(k0 + j) * fs]);
    }
    return r;
}

template<bool WS>
__launch_bounds__(512, 2)
__global__ void energy_mfma(
    const float* __restrict__ h_stack, const float* __restrict__ base_conf,
    const float* __restrict__ kW1, const float* __restrict__ kb1,
    const float* __restrict__ kW2, const float* __restrict__ kb2,
    const float* __restrict__ lW1, const float* __restrict__ lb1,
    const float* __restrict__ lW2, const float* __restrict__ lb2,
    const float* __restrict__ dW1, const float* __restrict__ db1,
    const float* __restrict__ dW2, const float* __restrict__ db2,
    const float* __restrict__ kwp, const float* __restrict__ lwp,
    const float* __restrict__ iwp, const float* __restrict__ tmpp,
    const unsigned short* __restrict__ wsB,
    float* __restrict__ out)
{
    extern __shared__ char smem[];
    char* Ab = smem;
    float* stageBase = (float*)(smem + LDSA_BYTES);

    const int tid  = threadIdx.x;
    const int wv   = tid >> 6;
    const int ln   = tid & 63;
    const int lo16 = ln & 15;
    const int hi4  = ln >> 4;
    const unsigned xorv = (unsigned)((ln & 7) << 4);

    // ---------- stage A (4 batches x 11 rows x 1024) as bf16, XOR-swizzled ----------
    {
        const size_t hbase = (size_t)blockIdx.x * (ROWS * 1024);
        #pragma unroll
        for (int i = 0; i < 11; ++i) {
            int idx = tid + i * 512;
            int row = idx >> 7;
            int kc  = idx & 127;
            const float* src = h_stack + hbase + (size_t)row * 1024 + kc * 8;
            float4 a = *(const float4*)src;
            float4 b = *(const float4*)(src + 4);
            bf16x8 v;
            v[0] = (short)f32_to_bf16u(a.x); v[1] = (short)f32_to_bf16u(a.y);
            v[2] = (short)f32_to_bf16u(a.z); v[3] = (short)f32_to_bf16u(a.w);
            v[4] = (short)f32_to_bf16u(b.x); v[5] = (short)f32_to_bf16u(b.y);
            v[6] = (short)f32_to_bf16u(b.z); v[7] = (short)f32_to_bf16u(b.w);
            unsigned kbyte = ((unsigned)(kc * 16)) ^ ((unsigned)((row & 7) << 4));
            *(bf16x8*)(Ab + row * 2048 + kbyte) = v;
        }
        { // zero pad rows 44..47
            int row = ROWS + (tid >> 7);
            int kc  = tid & 127;
            unsigned kbyte = ((unsigned)(kc * 16)) ^ ((unsigned)((row & 7) << 4));
            bf16x8 z = {0,0,0,0,0,0,0,0};
            *(bf16x8*)(Ab + row * 2048 + kbyte) = z;
        }
    }
    __syncthreads();

    float kin_part = 0.f, loc_part = 0.f;
    float accP[55];
    #pragma unroll
    for (int p = 0; p < 55; ++p) accP[p] = 0.f;

    float* stg0 = stageBase + wv * STG_WAVE;
    float* stg1 = stg0 + STG_TILE;

    auto readA = [&](int m, int kk) -> bf16x8 {
        unsigned addr = (unsigned)((16 * m + lo16) * 2048)
                      + ((unsigned)(kk * 64 + hi4 * 16) ^ xorv);
        return *(const bf16x8*)(Ab + addr);
    };

    // 48 quad-units: 0..7 kinetic, 8..15 local, 16..47 interaction (2 d-blocks each)
    #pragma unroll 1
    for (int ui = 0; ui < 6; ++ui) {
        const int u = wv + ui * 8;
        int c0, c1, c2, c3;
        if (u < 8)       { int base = u * 64;          c0 = base; c1 = base + 16; c2 = base + 32; c3 = base + 48; }
        else if (u < 16) { int base = 512 + (u - 8) * 64; c0 = base; c1 = base + 16; c2 = base + 32; c3 = base + 48; }
        else             { int v = u - 16; int d0 = 2 * v, d1 = 2 * v + 1;
                           c0 = 1024 + d0 * 16; c1 = 2048 + d0 * 16;
                           c2 = 1024 + d1 * 16; c3 = 2048 + d1 * 16; }

        const unsigned short *bp0 = nullptr, *bp1 = nullptr, *bp2 = nullptr, *bp3 = nullptr;
        const float *fp0 = nullptr, *fp1 = nullptr, *fp2 = nullptr, *fp3 = nullptr;
        int fs = 512;
        if constexpr (WS) {
            bp0 = wsB + (size_t)(c0 + lo16) * 1024;
            bp1 = wsB + (size_t)(c1 + lo16) * 1024;
            bp2 = wsB + (size_t)(c2 + lo16) * 1024;
            bp3 = wsB + (size_t)(c3 + lo16) * 1024;
        } else {
            if (u < 8)       { fp0 = kW1 + c0 + lo16; fp1 = kW1 + c1 + lo16; fp2 = kW1 + c2 + lo16; fp3 = kW1 + c3 + lo16; fs = 512; }
            else if (u < 16) { fp0 = lW1 + (c0 - 512) + lo16; fp1 = lW1 + (c1 - 512) + lo16;
                               fp2 = lW1 + (c2 - 512) + lo16; fp3 = lW1 + (c3 - 512) + lo16; fs = 512; }
            else             { fp0 = dW1 + (c0 - 1024) + lo16; fp1 = dW1 + (size_t)1024 * 1024 + (c1 - 2048) + lo16;
                               fp2 = dW1 + (c2 - 1024) + lo16; fp3 = dW1 + (size_t)1024 * 1024 + (c3 - 2048) + lo16; fs = 1024; }
        }

        f32x4 acc[4][3];
        #pragma unroll
        for (int q = 0; q < 4; ++q)
            #pragma unroll
            for (int m = 0; m < 3; ++m) acc[q][m] = (f32x4){0.f, 0.f, 0.f, 0.f};

        #pragma unroll 2
        for (int kk = 0; kk < 32; ++kk) {
            const int k0 = kk * 32 + hi4 * 8;
            bf16x8 b0 = loadB<WS>(bp0, fp0, fs, k0);
            bf16x8 b1 = loadB<WS>(bp1, fp1, fs, k0);
            bf16x8 b2 = loadB<WS>(bp2, fp2, fs, k0);
            bf16x8 b3 = loadB<WS>(bp3, fp3, fs, k0);
            bf16x8 a0 = readA(0, kk);
            bf16x8 a1 = readA(1, kk);
            bf16x8 a2 = readA(2, kk);
            acc[0][0] = __builtin_amdgcn_mfma_f32_16x16x32_bf16(a0, b0, acc[0][0], 0, 0, 0);
            acc[0][1] = __builtin_amdgcn_mfma_f32_16x16x32_bf16(a1, b0, acc[0][1], 0, 0, 0);
            acc[0][2] = __builtin_amdgcn_mfma_f32_16x16x32_bf16(a2, b0, acc[0][2], 0, 0, 0);
            acc[1][0] = __builtin_amdgcn_mfma_f32_16x16x32_bf16(a0, b1, acc[1][0], 0, 0, 0);
            acc[1][1] = __builtin_amdgcn_mfma_f32_16x16x32_bf16(a1, b1, acc[1][1], 0, 0, 0);
            acc[1][2] = __builtin_amdgcn_mfma_f32_16x16x32_bf16(a2, b1, acc[1][2], 0, 0, 0);
            acc[2][0] = __builtin_amdgcn_mfma_f32_16x16x32_bf16(a0, b2, acc[2][0], 0, 0, 0);
            acc[2][1] = __builtin_amdgcn_mfma_f32_16x16x32_bf16(a1, b2, acc[2][1], 0, 0, 0);
            acc[2][2] = __builtin_amdgcn_mfma_f32_16x16x32_bf16(a2, b2, acc[2][2], 0, 0, 0);
            acc[3][0] = __builtin_amdgcn_mfma_f32_16x16x32_bf16(a0, b3, acc[3][0], 0, 0, 0);
            acc[3][1] = __builtin_amdgcn_mfma_f32_16x16x32_bf16(a1, b3, acc[3][1], 0, 0, 0);
            acc[3][2] = __builtin_amdgcn_mfma_f32_16x16x32_bf16(a2, b3, acc[3][2], 0, 0, 0);
        }

        if (u < 16) {
            // kinetic / local: fold relu(pre + b1)*w2 then per-row sums
            const float* b1arr = (u < 8) ? kb1 : lb1;
            const float* w2arr = (u < 8) ? kW2 : lW2;
            const int colrel0 = (u < 8) ? c0 : (c0 - 512);
            float part = 0.f;
            #pragma unroll
            for (int q = 0; q < 4; ++q) {
                const int colrel = colrel0 + q * 16 + lo16;
                const float b1v = b1arr[colrel];
                const float w2v = w2arr[colrel];
                float* sb = (q & 1) ? stg1 : stg0;
                #pragma unroll
                for (int m = 0; m < 3; ++m)
                    #pragma unroll
                    for (int r = 0; r < 4; ++r) {
                        const int row = 16 * m + 4 * hi4 + r;
                        sb[row * 20 + lo16] = fmaxf(acc[q][m][r] + b1v, 0.f) * w2v;
                    }
                asm volatile("s_waitcnt lgkmcnt(0)" ::: "memory");
                if (ln < ROWS) {
                    const f32x4* rp = (const f32x4*)(sb + ln * 20);
                    float s = 0.f;
                    #pragma unroll
                    for (int c4 = 0; c4 < 4; ++c4) {
                        f32x4 vv = rp[c4];
                        s += vv[0] + vv[1] + vv[2] + vv[3];
                    }
                    part += s;
                }
            }
            if (u < 8) kin_part += part; else loc_part += part;
        } else {
            // interaction: stage raw pre_i/pre_j, combine per (b=hi4, d=lo16)
            const int v = u - 16;
            #pragma unroll
            for (int half = 0; half < 2; ++half) {
                const int dcol = (2 * v + half) * 16 + lo16;
                const float db1v = db1[dcol];
                const float dw2v = dW2[dcol];
                #pragma unroll
                for (int m = 0; m < 3; ++m)
                    #pragma unroll
                    for (int r = 0; r < 4; ++r) {
                        const int row = 16 * m + 4 * hi4 + r;
                        stg0[row * 20 + lo16] = acc[2 * half + 0][m][r];
                        stg1[row * 20 + lo16] = acc[2 * half + 1][m][r];
                    }
                asm volatile("s_waitcnt lgkmcnt(0)" ::: "memory");
                float pi[11], pj[11];
                #pragma unroll
                for (int t = 0; t < 11; ++t) {
                    const int row = 11 * hi4 + t;
                    pi[t] = stg0[row * 20 + lo16] + db1v;
                    pj[t] = stg1[row * 20 + lo16];
                }
                asm volatile("s_waitcnt lgkmcnt(0)" ::: "memory");
                #pragma unroll
                for (int p = 0; p < 55; ++p) {
                    const float s = pi[II_[p]] + pj[JJ_[p]];
                    accP[p] = fmaf(fmaxf(s, 0.f), dw2v, accP[p]);
                }
            }
        }
    }

    // ---------- block-level reduction ----------
    __syncthreads();
    float* kinbuf  = stageBase;               // [8][64]
    float* locbuf  = stageBase + 512;         // [8][64]
    float* pairbuf = stageBase + 1024;        // [8][4][56]
    float* pairres = stageBase + 2816;        // [4][56]
    float* kinrow  = stageBase + 3040;        // [48]
    float* locrow  = stageBase + 3104;        // [48]

    kinbuf[wv * 64 + ln] = kin_part;
    locbuf[wv * 64 + ln] = loc_part;
    #pragma unroll
    for (int p = 0; p < 55; ++p) {
        float vsum = accP[p];
        vsum += __shfl_xor(vsum, 1);
        vsum += __shfl_xor(vsum, 2);
        vsum += __shfl_xor(vsum, 4);
        vsum += __shfl_xor(vsum, 8);
        if (lo16 == 0) pairbuf[wv * 224 + hi4 * 56 + p] = vsum;
    }
    __syncthreads();

    if (tid < 220) {
        const int b = tid / 55, p = tid % 55;
        float s = db2[0];
        #pragma unroll
        for (int w = 0; w < 8; ++w) s += pairbuf[w * 224 + b * 56 + p];
        s = fmaxf(s, 0.f);
        const float dw = 1.0f / (float)(JJ_[p] - II_[p] + 1);
        pairres[b * 56 + p] = s * dw;
    }
    if (tid >= 256 && tid < 304) {
        const int r = tid - 256;
        float sk = 0.f, sl = 0.f;
        #pragma unroll
        for (int w = 0; w < 8; ++w) { sk += kinbuf[w * 64 + r]; sl += locbuf[w * 64 + r]; }
        kinrow[r] = sk; locrow[r] = sl;
    }
    __syncthreads();

    if (tid < 4) {
        const int b = tid;
        const float kw = kwp[0], lw = lwp[0], iw = iwp[0], temp = tmpp[0];
        float ks = 0.f;
        #pragma unroll
        for (int t = 0; t < 11; ++t) ks += kinrow[11 * b + t];
        const float kinetic = -kw * (ks * (1.f / 11.f) + kb2[0]);
        float ls = 0.f;
        #pragma unroll
        for (int t = 0; t < 11; ++t) ls += fmaxf(locrow[11 * b + t] + lb2[0], 0.f);
        const float local_e = lw * (ls * (1.f / 11.f));
        float is = 0.f;
        #pragma unroll
        for (int p = 0; p < 55; ++p) is += pairres[b * 56 + p];
        const float inter = iw * (is * (1.f / 55.f));
        const float total = kinetic + local_e + inter;
        const float ec = 1.f / (1.f + expf(total / (fabsf(temp) + 0.1f)));
        const int gb = blockIdx.x * 4 + b;
        out[0 * NBATCH + gb] = total;
        out[1 * NBATCH + gb] = kinetic;
        out[2 * NBATCH + gb] = local_e;
        out[3 * NBATCH + gb] = inter;
        out[4 * NBATCH + gb] = ec;
        out[5 * NBATCH + gb] = base_conf[gb] * ec;
    }
}

extern "C" void kernel_launch(void* const* d_in, const int* in_sizes, int n_in,
                              void* d_out, int out_size, void* d_ws, size_t ws_size,
                              hipStream_t stream) {
    const float* h_stack   = (const float*)d_in[0];
    const float* base_conf = (const float*)d_in[1];
    const float* kW1 = (const float*)d_in[2];
    const float* kb1 = (const float*)d_in[3];
    const float* kW2 = (const float*)d_in[4];
    const float* kb2 = (const float*)d_in[5];
    const float* lW1 = (const float*)d_in[6];
    const float* lb1 = (const float*)d_in[7];
    const float* lW2 = (const float*)d_in[8];
    const float* lb2 = (const float*)d_in[9];
    const float* dW1 = (const float*)d_in[10];
    const float* db1 = (const float*)d_in[11];
    const float* dW2 = (const float*)d_in[12];
    const float* db2 = (const float*)d_in[13];
    const float* kwp = (const float*)d_in[14];
    const float* lwp = (const float*)d_in[15];
    const float* iwp = (const float*)d_in[16];
    const float* tmpp= (const float*)d_in[17];
    float* out = (float*)d_out;

    const size_t wsNeeded = (size_t)3072 * 1024 * 2;
    if (ws_size >= wsNeeded) {
        hipLaunchKernelGGL(convert_weights, dim3(768), dim3(256), 0, stream,
                           kW1, lW1, dW1, (unsigned short*)d_ws);
        hipFuncSetAttribute((const void*)energy_mfma<true>,
                            hipFuncAttributeMaxDynamicSharedMemorySize, LDS_TOTAL);
        hipLaunchKernelGGL(energy_mfma<true>, dim3(512), dim3(512), LDS_TOTAL, stream,
                           h_stack, base_conf, kW1, kb1, kW2, kb2, lW1, lb1, lW2, lb2,
                           dW1, db1, dW2, db2, kwp, lwp, iwp, tmpp,
                           (const unsigned short*)d_ws, out);
    } else {
        hipFuncSetAttribute((const void*)energy_mfma<false>,
                            hipFuncAttributeMaxDynamicSharedMemorySize, LDS_TOTAL);
        hipLaunchKernelGGL(energy_mfma<false>, dim3(512), dim3(512), LDS_TOTAL, stream,
                           h_stack, base_conf, kW1, kb1, kW2, kb2, lW1, lb1, lW2, lb2,
                           dW1, db1, dW2, db2, kwp, lwp, iwp, tmpp,
                           (const unsigned short*)nullptr, out);
    }
}

// Round 3
// 262.056 us; speedup vs baseline: 9.8707x; 1.8497x over previous
//
#include <hip/hip_runtime.h>
#include <hip/hip_bf16.h>
#include <math.h>

typedef __attribute__((ext_vector_type(8))) short bf16x8;
typedef __attribute__((ext_vector_type(4))) float f32x4;

#define NBATCH   2048
#define GB       4
#define ROWS     44            // GB * 11
#define ROWSP    48            // padded to 3 M-tiles
#define LDSA_BYTES (ROWSP * 1024 * 2)          // 98304
#define STG_TILE   (ROWSP * 20)                // floats per stage tile
#define STG_WAVE   (2 * STG_TILE)              // 1920 floats per wave
#define LDS_TOTAL  (LDSA_BYTES + 8 * STG_WAVE * 4)   // 159744 <= 163840

// packed bf16 weights, MFMA-fragment-linear:
// group g (16 cols), kk (32 k-steps), lane(64): 8 u16 each
// col = g*16 + (lane&15); k = kk*32 + (lane>>4)*8 + j
__device__ unsigned short g_wsB2[(size_t)3072 * 1024];

static constexpr int II_[55] = {
    0,0,0,0,0,0,0,0,0,0, 1,1,1,1,1,1,1,1,1, 2,2,2,2,2,2,2,2,
    3,3,3,3,3,3,3, 4,4,4,4,4,4, 5,5,5,5,5, 6,6,6,6, 7,7,7, 8,8, 9};
static constexpr int JJ_[55] = {
    1,2,3,4,5,6,7,8,9,10, 2,3,4,5,6,7,8,9,10, 3,4,5,6,7,8,9,10,
    4,5,6,7,8,9,10, 5,6,7,8,9,10, 6,7,8,9,10, 7,8,9,10, 8,9,10, 9,10, 10};

__device__ __forceinline__ unsigned short f32_to_bf16u(float f) {
    unsigned u = __float_as_uint(f);
    u += 0x7fffu + ((u >> 16) & 1u);
    return (unsigned short)(u >> 16);
}

// pack f32 row-major weights -> fragment-linear bf16 (see g_wsB2 layout)
__global__ void pack_weights(const float* __restrict__ kW1,
                             const float* __restrict__ lW1,
                             const float* __restrict__ dW1) {
    const int t = blockIdx.x * 256 + threadIdx.x;     // 0..393215
    const int lane = t & 63;
    const int kk   = (t >> 6) & 31;
    const int g    = t >> 11;                          // 0..191
    const int col  = g * 16 + (lane & 15);
    const int k0   = kk * 32 + (lane >> 4) * 8;
    const float* src; int ncol, c;
    if (col < 512)       { src = kW1;                          ncol = 512;  c = col; }
    else if (col < 1024) { src = lW1;                          ncol = 512;  c = col - 512; }
    else if (col < 2048) { src = dW1;                          ncol = 1024; c = col - 1024; }
    else                 { src = dW1 + (size_t)1024 * 1024;    ncol = 1024; c = col - 2048; }
    bf16x8 v;
    #pragma unroll
    for (int j = 0; j < 8; ++j)
        v[j] = (short)f32_to_bf16u(src[(size_t)(k0 + j) * ncol + c]);
    *(bf16x8*)(g_wsB2 + (size_t)t * 8) = v;
}

__launch_bounds__(512, 2)
__global__ void energy_mfma(
    const float* __restrict__ h_stack, const float* __restrict__ base_conf,
    const float* __restrict__ kb1, const float* __restrict__ kW2,
    const float* __restrict__ kb2, const float* __restrict__ lb1,
    const float* __restrict__ lW2, const float* __restrict__ lb2,
    const float* __restrict__ db1, const float* __restrict__ dW2,
    const float* __restrict__ db2,
    const float* __restrict__ kwp, const float* __restrict__ lwp,
    const float* __restrict__ iwp, const float* __restrict__ tmpp,
    float* __restrict__ out)
{
    extern __shared__ char smem[];
    char* Ab = smem;
    float* stageBase = (float*)(smem + LDSA_BYTES);

    const int tid  = threadIdx.x;
    const int wv   = tid >> 6;
    const int ln   = tid & 63;
    const int lo16 = ln & 15;
    const int hi4  = ln >> 4;
    const unsigned xorv = (unsigned)((ln & 7) << 4);

    // ---------- stage A (4 batches x 11 rows x 1024) as bf16, XOR-swizzled ----------
    {
        const size_t hbase = (size_t)blockIdx.x * (ROWS * 1024);
        #pragma unroll
        for (int i = 0; i < 11; ++i) {
            int idx = tid + i * 512;
            int row = idx >> 7;
            int kc  = idx & 127;
            const float* src = h_stack + hbase + (size_t)row * 1024 + kc * 8;
            float4 a = *(const float4*)src;
            float4 b = *(const float4*)(src + 4);
            bf16x8 v;
            v[0] = (short)f32_to_bf16u(a.x); v[1] = (short)f32_to_bf16u(a.y);
            v[2] = (short)f32_to_bf16u(a.z); v[3] = (short)f32_to_bf16u(a.w);
            v[4] = (short)f32_to_bf16u(b.x); v[5] = (short)f32_to_bf16u(b.y);
            v[6] = (short)f32_to_bf16u(b.z); v[7] = (short)f32_to_bf16u(b.w);
            unsigned kbyte = ((unsigned)(kc * 16)) ^ ((unsigned)((row & 7) << 4));
            *(bf16x8*)(Ab + row * 2048 + kbyte) = v;
        }
        { // zero pad rows 44..47
            int row = ROWS + (tid >> 7);
            int kc  = tid & 127;
            unsigned kbyte = ((unsigned)(kc * 16)) ^ ((unsigned)((row & 7) << 4));
            bf16x8 z = {0,0,0,0,0,0,0,0};
            *(bf16x8*)(Ab + row * 2048 + kbyte) = z;
        }
    }
    __syncthreads();

    float kin_part = 0.f, loc_part = 0.f;
    float accP[55];
    #pragma unroll
    for (int p = 0; p < 55; ++p) accP[p] = 0.f;

    float* stg0 = stageBase + wv * STG_WAVE;
    float* stg1 = stg0 + STG_TILE;

    auto readA = [&](int m, int kk) -> bf16x8 {
        unsigned addr = (unsigned)((16 * m + lo16) * 2048)
                      + ((unsigned)(kk * 64 + hi4 * 16) ^ xorv);
        return *(const bf16x8*)(Ab + addr);
    };

    // 48 quad-units: 0..7 kinetic, 8..15 local, 16..47 interaction (2 d-cols each)
    #pragma unroll 1
    for (int ui = 0; ui < 6; ++ui) {
        const int u = wv + ui * 8;
        // fragment-group indices for the 4 column-groups of this unit
        int g0, g1, g2, g3;
        if (u < 16) { g0 = 4 * u; g1 = 4 * u + 1; g2 = 4 * u + 2; g3 = 4 * u + 3; }
        else        { int v = u - 16;
                      g0 = 64 + 2 * v; g1 = 128 + 2 * v;       // dW1a/dW1b col d0
                      g2 = 65 + 2 * v; g3 = 129 + 2 * v; }     // dW1a/dW1b col d1

        const unsigned short* bp0 = g_wsB2 + (size_t)g0 * 16384 + ln * 8;
        const unsigned short* bp1 = g_wsB2 + (size_t)g1 * 16384 + ln * 8;
        const unsigned short* bp2 = g_wsB2 + (size_t)g2 * 16384 + ln * 8;
        const unsigned short* bp3 = g_wsB2 + (size_t)g3 * 16384 + ln * 8;

        f32x4 acc[4][3];
        #pragma unroll
        for (int q = 0; q < 4; ++q)
            #pragma unroll
            for (int m = 0; m < 3; ++m) acc[q][m] = (f32x4){0.f, 0.f, 0.f, 0.f};

        auto ldB = [&](const unsigned short* p, int kk) -> bf16x8 {
            return *(const bf16x8*)(p + (size_t)kk * 512);
        };
        auto mfma12 = [&](bf16x8 a0, bf16x8 a1, bf16x8 a2,
                          bf16x8 b0, bf16x8 b1, bf16x8 b2, bf16x8 b3) {
            acc[0][0] = __builtin_amdgcn_mfma_f32_16x16x32_bf16(a0, b0, acc[0][0], 0, 0, 0);
            acc[0][1] = __builtin_amdgcn_mfma_f32_16x16x32_bf16(a1, b0, acc[0][1], 0, 0, 0);
            acc[0][2] = __builtin_amdgcn_mfma_f32_16x16x32_bf16(a2, b0, acc[0][2], 0, 0, 0);
            acc[1][0] = __builtin_amdgcn_mfma_f32_16x16x32_bf16(a0, b1, acc[1][0], 0, 0, 0);
            acc[1][1] = __builtin_amdgcn_mfma_f32_16x16x32_bf16(a1, b1, acc[1][1], 0, 0, 0);
            acc[1][2] = __builtin_amdgcn_mfma_f32_16x16x32_bf16(a2, b1, acc[1][2], 0, 0, 0);
            acc[2][0] = __builtin_amdgcn_mfma_f32_16x16x32_bf16(a0, b2, acc[2][0], 0, 0, 0);
            acc[2][1] = __builtin_amdgcn_mfma_f32_16x16x32_bf16(a1, b2, acc[2][1], 0, 0, 0);
            acc[2][2] = __builtin_amdgcn_mfma_f32_16x16x32_bf16(a2, b2, acc[2][2], 0, 0, 0);
            acc[3][0] = __builtin_amdgcn_mfma_f32_16x16x32_bf16(a0, b3, acc[3][0], 0, 0, 0);
            acc[3][1] = __builtin_amdgcn_mfma_f32_16x16x32_bf16(a1, b3, acc[3][1], 0, 0, 0);
            acc[3][2] = __builtin_amdgcn_mfma_f32_16x16x32_bf16(a2, b3, acc[3][2], 0, 0, 0);
        };

        // ---- software-pipelined K loop: B depth-2, A depth-1 prefetch ----
        bf16x8 A0 = readA(0, 0), A1 = readA(1, 0), A2 = readA(2, 0);
        bf16x8 B0 = ldB(bp0, 0), B1 = ldB(bp1, 0), B2 = ldB(bp2, 0), B3 = ldB(bp3, 0);
        bf16x8 C0 = ldB(bp0, 1), C1 = ldB(bp1, 1), C2 = ldB(bp2, 1), C3 = ldB(bp3, 1);

        #pragma unroll 2
        for (int kk = 0; kk < 31; ++kk) {
            bf16x8 a0 = A0, a1 = A1, a2 = A2;
            A0 = readA(0, kk + 1); A1 = readA(1, kk + 1); A2 = readA(2, kk + 1);
            bf16x8 b0 = B0, b1 = B1, b2 = B2, b3 = B3;
            B0 = C0; B1 = C1; B2 = C2; B3 = C3;
            if (kk < 30) {
                C0 = ldB(bp0, kk + 2); C1 = ldB(bp1, kk + 2);
                C2 = ldB(bp2, kk + 2); C3 = ldB(bp3, kk + 2);
            }
            mfma12(a0, a1, a2, b0, b1, b2, b3);
        }
        mfma12(A0, A1, A2, B0, B1, B2, B3);   // kk = 31

        if (u < 16) {
            // kinetic / local: fold relu(pre + b1)*w2 then per-row sums
            const float* b1arr = (u < 8) ? kb1 : lb1;
            const float* w2arr = (u < 8) ? kW2 : lW2;
            const int colrel0 = (u < 8) ? u * 64 : (u - 8) * 64;
            float part = 0.f;
            #pragma unroll
            for (int q = 0; q < 4; ++q) {
                const int colrel = colrel0 + q * 16 + lo16;
                const float b1v = b1arr[colrel];
                const float w2v = w2arr[colrel];
                float* sb = (q & 1) ? stg1 : stg0;
                #pragma unroll
                for (int m = 0; m < 3; ++m)
                    #pragma unroll
                    for (int r = 0; r < 4; ++r) {
                        const int row = 16 * m + 4 * hi4 + r;
                        sb[row * 20 + lo16] = fmaxf(acc[q][m][r] + b1v, 0.f) * w2v;
                    }
                asm volatile("s_waitcnt lgkmcnt(0)" ::: "memory");
                if (ln < ROWS) {
                    const f32x4* rp = (const f32x4*)(sb + ln * 20);
                    float s = 0.f;
                    #pragma unroll
                    for (int c4 = 0; c4 < 4; ++c4) {
                        f32x4 vv = rp[c4];
                        s += vv[0] + vv[1] + vv[2] + vv[3];
                    }
                    part += s;
                }
            }
            if (u < 8) kin_part += part; else loc_part += part;
        } else {
            // interaction: stage raw pre_i/pre_j, combine per (b=hi4, d=lo16)
            const int v = u - 16;
            #pragma unroll
            for (int half = 0; half < 2; ++half) {
                const int dcol = (2 * v + half) * 16 + lo16;
                const float db1v = db1[dcol];
                const float dw2v = dW2[dcol];
                #pragma unroll
                for (int m = 0; m < 3; ++m)
                    #pragma unroll
                    for (int r = 0; r < 4; ++r) {
                        const int row = 16 * m + 4 * hi4 + r;
                        stg0[row * 20 + lo16] = acc[2 * half + 0][m][r];
                        stg1[row * 20 + lo16] = acc[2 * half + 1][m][r];
                    }
                asm volatile("s_waitcnt lgkmcnt(0)" ::: "memory");
                float pi[11], pj[11];
                #pragma unroll
                for (int t = 0; t < 11; ++t) {
                    const int row = 11 * hi4 + t;
                    pi[t] = stg0[row * 20 + lo16] + db1v;
                    pj[t] = stg1[row * 20 + lo16];
                }
                asm volatile("s_waitcnt lgkmcnt(0)" ::: "memory");
                #pragma unroll
                for (int p = 0; p < 55; ++p) {
                    const float s = pi[II_[p]] + pj[JJ_[p]];
                    accP[p] = fmaf(fmaxf(s, 0.f), dw2v, accP[p]);
                }
            }
        }
    }

    // ---------- block-level reduction ----------
    __syncthreads();
    float* kinbuf  = stageBase;               // [8][64]
    float* locbuf  = stageBase + 512;         // [8][64]
    float* pairbuf = stageBase + 1024;        // [8][4][56]
    float* pairres = stageBase + 2816;        // [4][56]
    float* kinrow  = stageBase + 3040;        // [48]
    float* locrow  = stageBase + 3104;        // [48]

    kinbuf[wv * 64 + ln] = kin_part;
    locbuf[wv * 64 + ln] = loc_part;
    #pragma unroll
    for (int p = 0; p < 55; ++p) {
        float vsum = accP[p];
        vsum += __shfl_xor(vsum, 1);
        vsum += __shfl_xor(vsum, 2);
        vsum += __shfl_xor(vsum, 4);
        vsum += __shfl_xor(vsum, 8);
        if (lo16 == 0) pairbuf[wv * 224 + hi4 * 56 + p] = vsum;
    }
    __syncthreads();

    if (tid < 220) {
        const int b = tid / 55, p = tid % 55;
        float s = db2[0];
        #pragma unroll
        for (int w = 0; w < 8; ++w) s += pairbuf[w * 224 + b * 56 + p];
        s = fmaxf(s, 0.f);
        const float dw = 1.0f / (float)(JJ_[p] - II_[p] + 1);
        pairres[b * 56 + p] = s * dw;
    }
    if (tid >= 256 && tid < 304) {
        const int r = tid - 256;
        float sk = 0.f, sl = 0.f;
        #pragma unroll
        for (int w = 0; w < 8; ++w) { sk += kinbuf[w * 64 + r]; sl += locbuf[w * 64 + r]; }
        kinrow[r] = sk; locrow[r] = sl;
    }
    __syncthreads();

    if (tid < 4) {
        const int b = tid;
        const float kw = kwp[0], lw = lwp[0], iw = iwp[0], temp = tmpp[0];
        float ks = 0.f;
        #pragma unroll
        for (int t = 0; t < 11; ++t) ks += kinrow[11 * b + t];
        const float kinetic = -kw * (ks * (1.f / 11.f) + kb2[0]);
        float ls = 0.f;
        #pragma unroll
        for (int t = 0; t < 11; ++t) ls += fmaxf(locrow[11 * b + t] + lb2[0], 0.f);
        const float local_e = lw * (ls * (1.f / 11.f));
        float is = 0.f;
        #pragma unroll
        for (int p = 0; p < 55; ++p) is += pairres[b * 56 + p];
        const float inter = iw * (is * (1.f / 55.f));
        const float total = kinetic + local_e + inter;
        const float ec = 1.f / (1.f + expf(total / (fabsf(temp) + 0.1f)));
        const int gb = blockIdx.x * 4 + b;
        out[0 * NBATCH + gb] = total;
        out[1 * NBATCH + gb] = kinetic;
        out[2 * NBATCH + gb] = local_e;
        out[3 * NBATCH + gb] = inter;
        out[4 * NBATCH + gb] = ec;
        out[5 * NBATCH + gb] = base_conf[gb] * ec;
    }
}

extern "C" void kernel_launch(void* const* d_in, const int* in_sizes, int n_in,
                              void* d_out, int out_size, void* d_ws, size_t ws_size,
                              hipStream_t stream) {
    const float* h_stack   = (const float*)d_in[0];
    const float* base_conf = (const float*)d_in[1];
    const float* kW1 = (const float*)d_in[2];
    const float* kb1 = (const float*)d_in[3];
    const float* kW2 = (const float*)d_in[4];
    const float* kb2 = (const float*)d_in[5];
    const float* lW1 = (const float*)d_in[6];
    const float* lb1 = (const float*)d_in[7];
    const float* lW2 = (const float*)d_in[8];
    const float* lb2 = (const float*)d_in[9];
    const float* dW1 = (const float*)d_in[10];
    const float* db1 = (const float*)d_in[11];
    const float* dW2 = (const float*)d_in[12];
    const float* db2 = (const float*)d_in[13];
    const float* kwp = (const float*)d_in[14];
    const float* lwp = (const float*)d_in[15];
    const float* iwp = (const float*)d_in[16];
    const float* tmpp= (const float*)d_in[17];
    float* out = (float*)d_out;

    hipLaunchKernelGGL(pack_weights, dim3(1536), dim3(256), 0, stream, kW1, lW1, dW1);

    hipFuncSetAttribute((const void*)energy_mfma,
                        hipFuncAttributeMaxDynamicSharedMemorySize, LDS_TOTAL);
    hipLaunchKernelGGL(energy_mfma, dim3(512), dim3(512), LDS_TOTAL, stream,
                       h_stack, base_conf, kb1, kW2, kb2, lb1, lW2, lb2,
                       db1, dW2, db2, kwp, lwp, iwp, tmpp, out);
}